// Round 10
// baseline (111.324 us; speedup 1.0000x reference)
//
#include <hip/hip_runtime.h>
#include <stdint.h>

#define N_ROWS 8192
#define FEAT   256
#define RB     128                    // rows per unit block
#define NB     (N_ROWS / RB)          // 64 row-blocks
#define NPAIR  (NB * (NB + 1) / 2)    // 2080 (a<=b) pairs
#define NSLOT  NB                     // 64 partial slots per row (packed)
#define CT     64                     // cols staged per chunk (32 KB)

typedef __bf16 bf16x8 __attribute__((ext_vector_type(8)));
typedef float  f32x4  __attribute__((ext_vector_type(4)));

__device__ __forceinline__ unsigned short f2bf(float x) {
    union { float f; uint32_t u; } v; v.f = x;
    uint32_t u = v.u;
    return (unsigned short)((u + 0x7FFFu + ((u >> 16) & 1u)) >> 16);
}

__device__ __forceinline__ void gld16(const unsigned short* g, unsigned short* l) {
    // direct global->LDS, 16 B per lane; LDS dest wave-linear (it is)
    __builtin_amdgcn_global_load_lds((__attribute__((address_space(1))) void*)g,
                                     (__attribute__((address_space(3))) void*)l,
                                     16, 0, 0);
}

// ---- Kernel 1: normalize rows -> bf16 copy (16B-chunk XOR-swizzled rows);
//      fused positive-pair dot. 4 waves/block = 4 consecutive rows.
__global__ void knorm(const float* __restrict__ feat,
                      unsigned short* __restrict__ fb,
                      float* __restrict__ pos) {
    __shared__ float ex[4][FEAT];
    int wave = threadIdx.x >> 6;
    int lane = threadIdx.x & 63;
    int row  = blockIdx.x * 4 + wave;
    float4 v = ((const float4*)(feat + row * FEAT))[lane];
    float ss = v.x*v.x + v.y*v.y + v.z*v.z + v.w*v.w;
    #pragma unroll
    for (int off = 1; off < 64; off <<= 1) ss += __shfl_xor(ss, off);
    float inv = 1.0f / fmaxf(sqrtf(ss), 1e-12f);
    float4 o; o.x = v.x*inv; o.y = v.y*inv; o.z = v.z*inv; o.w = v.w*inv;
    ushort4 b;
    b.x = f2bf(o.x); b.y = f2bf(o.y); b.z = f2bf(o.z); b.w = f2bf(o.w);
    int sidx = (((lane >> 1) ^ (row & 7)) << 1) | (lane & 1);
    ((ushort4*)(fb + row * FEAT))[sidx] = b;
    ((float4*)ex[wave])[lane] = o;
    __syncthreads();
    float4 p = ((float4*)ex[wave ^ 1])[lane];
    float d = o.x*p.x + o.y*p.y + o.z*p.z + o.w*p.w;
    #pragma unroll
    for (int off = 1; off < 64; off <<= 1) d += __shfl_xor(d, off);
    if (lane == 0) pos[row] = d;
}

// ---- Kernel 2: SYMMETRIC LDS-staged f@f^T exp-sum, 64-row waves ----------
// R9 structure (symmetric (a<=b) 128x128 units, single-buffer LDS staging,
// packed slot scheme: row-sums -> slot b, col-sums -> slot a, diag row-only)
// with the DS term halved: 2 waves x 64 rows (af[4][8]) so each B-fragment
// ds_read_b128 feeds 4 MFMAs instead of 2 (Sigma-model: DS 10.4 -> 5.2 us,
// the largest non-MFMA term). Residency preserved: 128-thr blocks,
// launch_bounds(128,2) -> VGPR cap 256 (~190 needed), LDS 34 KB ->
// 4 blocks/CU = 8 waves/CU, intra-block barriers covered by 3 other
// independent-phase blocks (m114).
__global__ __launch_bounds__(128, 2)
void kmain(const unsigned short* __restrict__ fb, float* __restrict__ partial) {
    __shared__ unsigned short buf[CT * FEAT];    // 32 KB (single buffer)
    __shared__ float colred[2][RB];              //  1 KB
    const int t    = threadIdx.x;
    const int lane = t & 63;
    const int wave = t >> 6;          // 0..1
    const int quad = lane >> 4;       // 0..3
    const int l15  = lane & 15;

    // decode blockIdx.x -> (a, b): pair index row-major over a<=b
    int a = 0, rem = blockIdx.x;
    while (rem >= NB - a) { rem -= NB - a; ++a; }
    const int b = a + rem;
    const bool isdiag = (a == b);

    const int rw    = a * RB + wave * 64;        // this wave's 64 A-rows
    const int cbase = b * RB;                    // this unit's 128 B-cols
    const float Kc = 20.60992915555662f;         // log2(e)/0.07

#define STAGE(CC0) do {                                                       \
    const unsigned short* sp_ = fb + (size_t)(cbase + (CC0)) * FEAT + t * 8;  \
    unsigned short* dp_ = buf + t * 8;                                        \
    _Pragma("unroll")                                                         \
    for (int i_ = 0; i_ < 16; ++i_)                                           \
        gld16(sp_ + i_ * 1024, dp_ + i_ * 1024);                              \
} while (0)

    STAGE(0);          // chunk 0 in flight while we load A fragments

    // A fragments: 64 rows x K=256 resident in registers (128 VGPRs)
    bf16x8 af[4][8];
    #pragma unroll
    for (int rf = 0; rf < 4; ++rf)
        #pragma unroll
        for (int ks = 0; ks < 8; ++ks) {
            int row = rw + rf * 16 + l15;
            int ch  = (ks * 4 + quad) ^ (row & 7);   // undo layout swizzle
            af[rf][ks] = *(const bf16x8*)(fb + row * FEAT + ch * 8);
        }

    float lsum[4][4] = {{0.f,0.f,0.f,0.f},{0.f,0.f,0.f,0.f},
                        {0.f,0.f,0.f,0.f},{0.f,0.f,0.f,0.f}};
    float cs[8] = {0.f,0.f,0.f,0.f,0.f,0.f,0.f,0.f};

    // one 64-col chunk from LDS: 4 groups of 16 cols; B-frag feeds 4 MFMAs
#define COMPUTE(CC0, CS0) do {                                                \
    _Pragma("unroll")                                                         \
    for (int g = 0; g < 4; ++g) {                                             \
        const int cg = cbase + (CC0) + g * 16;                                \
        const int C  = cg + l15;                                              \
        f32x4 ac0 = {0.f,0.f,0.f,0.f};                                        \
        f32x4 ac1 = {0.f,0.f,0.f,0.f};                                        \
        f32x4 ac2 = {0.f,0.f,0.f,0.f};                                        \
        f32x4 ac3 = {0.f,0.f,0.f,0.f};                                        \
        _Pragma("unroll")                                                     \
        for (int ks = 0; ks < 8; ++ks) {                                      \
            bf16x8 bv = *(const bf16x8*)(buf + (g * 16 + l15) * FEAT          \
                                        + (((ks * 4 + quad) ^ (l15 & 7)) * 8)); \
            ac0 = __builtin_amdgcn_mfma_f32_16x16x32_bf16(af[0][ks], bv, ac0, 0, 0, 0); \
            ac1 = __builtin_amdgcn_mfma_f32_16x16x32_bf16(af[1][ks], bv, ac1, 0, 0, 0); \
            ac2 = __builtin_amdgcn_mfma_f32_16x16x32_bf16(af[2][ks], bv, ac2, 0, 0, 0); \
            ac3 = __builtin_amdgcn_mfma_f32_16x16x32_bf16(af[3][ks], bv, ac3, 0, 0, 0); \
        }                                                                     \
        _Pragma("unroll")                                                     \
        for (int rf = 0; rf < 4; ++rf) {                                      \
            const int rb_ = rw + rf * 16;                                     \
            const bool dg_ = (cg == rb_);   /* only on diagonal units */      \
            const f32x4 ac = (rf == 0) ? ac0 : (rf == 1) ? ac1                \
                           : (rf == 2) ? ac2 : ac3;                           \
            _Pragma("unroll")                                                 \
            for (int r = 0; r < 4; ++r) {                                     \
                float e = __builtin_amdgcn_exp2f(fmaf(ac[r], Kc, -Kc));       \
                if (dg_ && (rb_ + quad * 4 + r == C)) e = 0.f; /* j == i */   \
                lsum[rf][r] += e;                                             \
                cs[(CS0) + g] += e;                                           \
            }                                                                 \
        }                                                                     \
    }                                                                         \
} while (0)

    asm volatile("s_waitcnt vmcnt(0)" ::: "memory");
    __builtin_amdgcn_s_barrier();
    COMPUTE(0, 0);                   // chunk 0
    __builtin_amdgcn_s_barrier();    // all waves done reading buf
    STAGE(CT);                       // chunk 1
    asm volatile("s_waitcnt vmcnt(0)" ::: "memory");
    __builtin_amdgcn_s_barrier();
    COMPUTE(CT, 4);                  // chunk 1

    // ---- row sums -> partial[b][rows of a] -------------------------------
    #pragma unroll
    for (int rf = 0; rf < 4; ++rf)
        #pragma unroll
        for (int r = 0; r < 4; ++r) {
            float v = lsum[rf][r];
            v += __shfl_xor(v, 1);
            v += __shfl_xor(v, 2);
            v += __shfl_xor(v, 4);
            v += __shfl_xor(v, 8);
            lsum[rf][r] = v;
        }
    if (l15 == 0) {
        #pragma unroll
        for (int rf = 0; rf < 4; ++rf)
            #pragma unroll
            for (int r = 0; r < 4; ++r) {
                int row = rw + rf * 16 + quad * 4 + r;
                partial[b * N_ROWS + row] = lsum[rf][r];
            }
    }

    // ---- col sums -> partial[a][rows of b] (skip on diagonal) ------------
    #pragma unroll
    for (int g = 0; g < 8; ++g) {
        float v = cs[g];
        v += __shfl_xor(v, 16);      // sum across quads (rows, same col)
        v += __shfl_xor(v, 32);
        if (lane < 16) colred[wave][g * 16 + l15] = v;
    }
    __syncthreads();
    if (!isdiag) {
        float s = colred[0][t] + colred[1][t];
        partial[a * N_ROWS + b * RB + t] = s;
    }
}

// ---- Kernel 3: per-row loss. 128 blocks x 256 thr; wave w sums slots
// w*16..w*16+15 for 64 rows (coalesced 256B loads), combine via LDS.
__global__ void kreduce(const float* __restrict__ partial,
                        const float* __restrict__ pos,
                        float* __restrict__ bsum) {
    __shared__ float red[4][64];
    int wave = threadIdx.x >> 6;
    int lane = threadIdx.x & 63;
    int row0 = blockIdx.x * 64;
    float L = 0.f;
    #pragma unroll
    for (int p = 0; p < 16; ++p)
        L += partial[(size_t)(wave * 16 + p) * N_ROWS + row0 + lane];
    red[wave][lane] = L;
    __syncthreads();
    if (wave == 0) {
        float Lt = red[0][lane] + red[1][lane] + red[2][lane] + red[3][lane];
        int row = row0 + lane;
        const float invT = 14.285714285714286f;
        // loss_i = (1 - pos_i)/T + ln2 * log2(L)   (v_log_f32 is log2)
        float loss = invT * (1.0f - pos[row])
                   + 0.6931471805599453f * __builtin_amdgcn_logf(Lt);
        #pragma unroll
        for (int off = 1; off < 64; off <<= 1) loss += __shfl_xor(loss, off);
        if (lane == 0) bsum[blockIdx.x] = loss;
    }
}

// ---- Kernel 4: final 128 -> 1 --------------------------------------------
__global__ void kfinal(const float* __restrict__ bsum, float* __restrict__ out) {
    int lane = threadIdx.x;
    float v = bsum[lane] + bsum[lane + 64];
    #pragma unroll
    for (int off = 1; off < 64; off <<= 1) v += __shfl_xor(v, off);
    if (lane == 0) out[0] = v * (1.0f / 8192.0f);
}

extern "C" void kernel_launch(void* const* d_in, const int* in_sizes, int n_in,
                              void* d_out, int out_size, void* d_ws, size_t ws_size,
                              hipStream_t stream) {
    const float* feat = (const float*)d_in[0];
    float* out = (float*)d_out;
    char* ws = (char*)d_ws;
    unsigned short* fb      = (unsigned short*)ws;                    // 4 MB bf16 (swizzled rows)
    float*          partial = (float*)(ws + (4u << 20));              // 2 MB (64 slots x 8192)
    float*          pos     = (float*)(ws + (6u << 20));              // 32 KB
    float*          bsum    = (float*)(ws + (6u << 20) + (1u << 15)); // 512 B

    knorm<<<N_ROWS / 4, 256, 0, stream>>>(feat, fb, pos);
    kmain<<<NPAIR, 128, 0, stream>>>(fb, partial);
    kreduce<<<N_ROWS / 64, 256, 0, stream>>>(partial, pos, bsum);
    kfinal<<<1, 64, 0, stream>>>(bsum, out);
}

// Round 11
// 103.751 us; speedup vs baseline: 1.0730x; 1.0730x over previous
//
#include <hip/hip_runtime.h>
#include <stdint.h>

#define N_ROWS 8192
#define FEAT   256
#define RB     128                    // rows per unit block
#define NB     (N_ROWS / RB)          // 64 row-blocks
#define NPAIR  (NB * (NB + 1) / 2)    // 2080 (a<=b) pairs
#define NSLOT  NB                     // 64 partial slots per row (packed)
#define CT     64                     // cols staged per chunk (32 KB)

typedef __bf16 bf16x8 __attribute__((ext_vector_type(8)));
typedef float  f32x4  __attribute__((ext_vector_type(4)));

__device__ __forceinline__ unsigned short f2bf(float x) {
    union { float f; uint32_t u; } v; v.f = x;
    uint32_t u = v.u;
    return (unsigned short)((u + 0x7FFFu + ((u >> 16) & 1u)) >> 16);
}

__device__ __forceinline__ void gld16(const unsigned short* g, unsigned short* l) {
    // direct global->LDS, 16 B per lane; LDS dest wave-linear (it is)
    __builtin_amdgcn_global_load_lds((__attribute__((address_space(1))) void*)g,
                                     (__attribute__((address_space(3))) void*)l,
                                     16, 0, 0);
}

// ---- Kernel 1: normalize rows -> bf16 copy (16B-chunk XOR-swizzled rows);
//      fused positive-pair dot. 4 waves/block = 4 consecutive rows.
__global__ void knorm(const float* __restrict__ feat,
                      unsigned short* __restrict__ fb,
                      float* __restrict__ pos) {
    __shared__ float ex[4][FEAT];
    int wave = threadIdx.x >> 6;
    int lane = threadIdx.x & 63;
    int row  = blockIdx.x * 4 + wave;
    float4 v = ((const float4*)(feat + row * FEAT))[lane];
    float ss = v.x*v.x + v.y*v.y + v.z*v.z + v.w*v.w;
    #pragma unroll
    for (int off = 1; off < 64; off <<= 1) ss += __shfl_xor(ss, off);
    float inv = 1.0f / fmaxf(sqrtf(ss), 1e-12f);
    float4 o; o.x = v.x*inv; o.y = v.y*inv; o.z = v.z*inv; o.w = v.w*inv;
    ushort4 b;
    b.x = f2bf(o.x); b.y = f2bf(o.y); b.z = f2bf(o.z); b.w = f2bf(o.w);
    int sidx = (((lane >> 1) ^ (row & 7)) << 1) | (lane & 1);
    ((ushort4*)(fb + row * FEAT))[sidx] = b;
    ((float4*)ex[wave])[lane] = o;
    __syncthreads();
    float4 p = ((float4*)ex[wave ^ 1])[lane];
    float d = o.x*p.x + o.y*p.y + o.z*p.z + o.w*p.w;
    #pragma unroll
    for (int off = 1; off < 64; off <<= 1) d += __shfl_xor(d, off);
    if (lane == 0) pos[row] = d;
}

// ---- Kernel 2: SYMMETRIC LDS-staged f@f^T exp-sum, 64-row waves ----------
// R9 structure (symmetric (a<=b) 128x128 units, single-buffer LDS staging,
// packed slot scheme: row-sums -> slot b, col-sums -> slot a, diag row-only)
// with the DS term halved: 2 waves x 64 rows (af[4][8]) so each B-fragment
// ds_read_b128 feeds 4 MFMAs instead of 2.
// launch_bounds(128,1): min-waves >= 2 on an MFMA kernel needing >128 arch
// regs makes the allocator split the budget 128 arch + 128 acc and SPILL
// (R1: (256,2) -> 41MB scratch; R10: (128,2) -> 68MB scratch). min-waves=1
// uncaps it (R2 precedent: 172 regs, no spill); at ~200 VGPR the runtime
// still fits 2 waves/SIMD = 8 waves/CU = 4 blocks/CU (LDS 33KB also allows
// 4), preserving R9's residency with half the DS instructions.
__global__ __launch_bounds__(128, 1)
void kmain(const unsigned short* __restrict__ fb, float* __restrict__ partial) {
    __shared__ unsigned short buf[CT * FEAT];    // 32 KB (single buffer)
    __shared__ float colred[2][RB];              //  1 KB
    const int t    = threadIdx.x;
    const int lane = t & 63;
    const int wave = t >> 6;          // 0..1
    const int quad = lane >> 4;       // 0..3
    const int l15  = lane & 15;

    // decode blockIdx.x -> (a, b): pair index row-major over a<=b
    int a = 0, rem = blockIdx.x;
    while (rem >= NB - a) { rem -= NB - a; ++a; }
    const int b = a + rem;
    const bool isdiag = (a == b);

    const int rw    = a * RB + wave * 64;        // this wave's 64 A-rows
    const int cbase = b * RB;                    // this unit's 128 B-cols
    const float Kc = 20.60992915555662f;         // log2(e)/0.07

#define STAGE(CC0) do {                                                       \
    const unsigned short* sp_ = fb + (size_t)(cbase + (CC0)) * FEAT + t * 8;  \
    unsigned short* dp_ = buf + t * 8;                                        \
    _Pragma("unroll")                                                         \
    for (int i_ = 0; i_ < 16; ++i_)                                           \
        gld16(sp_ + i_ * 1024, dp_ + i_ * 1024);                              \
} while (0)

    STAGE(0);          // chunk 0 in flight while we load A fragments

    // A fragments: 64 rows x K=256 resident in registers (128 VGPRs)
    bf16x8 af[4][8];
    #pragma unroll
    for (int rf = 0; rf < 4; ++rf)
        #pragma unroll
        for (int ks = 0; ks < 8; ++ks) {
            int row = rw + rf * 16 + l15;
            int ch  = (ks * 4 + quad) ^ (row & 7);   // undo layout swizzle
            af[rf][ks] = *(const bf16x8*)(fb + row * FEAT + ch * 8);
        }

    float lsum[4][4] = {{0.f,0.f,0.f,0.f},{0.f,0.f,0.f,0.f},
                        {0.f,0.f,0.f,0.f},{0.f,0.f,0.f,0.f}};
    float cs[8] = {0.f,0.f,0.f,0.f,0.f,0.f,0.f,0.f};

    // one 64-col chunk from LDS: 4 groups of 16 cols; B-frag feeds 4 MFMAs
#define COMPUTE(CC0, CS0) do {                                                \
    _Pragma("unroll")                                                         \
    for (int g = 0; g < 4; ++g) {                                             \
        const int cg = cbase + (CC0) + g * 16;                                \
        const int C  = cg + l15;                                              \
        f32x4 ac0 = {0.f,0.f,0.f,0.f};                                        \
        f32x4 ac1 = {0.f,0.f,0.f,0.f};                                        \
        f32x4 ac2 = {0.f,0.f,0.f,0.f};                                        \
        f32x4 ac3 = {0.f,0.f,0.f,0.f};                                        \
        _Pragma("unroll")                                                     \
        for (int ks = 0; ks < 8; ++ks) {                                      \
            bf16x8 bv = *(const bf16x8*)(buf + (g * 16 + l15) * FEAT          \
                                        + (((ks * 4 + quad) ^ (l15 & 7)) * 8)); \
            ac0 = __builtin_amdgcn_mfma_f32_16x16x32_bf16(af[0][ks], bv, ac0, 0, 0, 0); \
            ac1 = __builtin_amdgcn_mfma_f32_16x16x32_bf16(af[1][ks], bv, ac1, 0, 0, 0); \
            ac2 = __builtin_amdgcn_mfma_f32_16x16x32_bf16(af[2][ks], bv, ac2, 0, 0, 0); \
            ac3 = __builtin_amdgcn_mfma_f32_16x16x32_bf16(af[3][ks], bv, ac3, 0, 0, 0); \
        }                                                                     \
        _Pragma("unroll")                                                     \
        for (int rf = 0; rf < 4; ++rf) {                                      \
            const int rb_ = rw + rf * 16;                                     \
            const bool dg_ = (cg == rb_);   /* only on diagonal units */      \
            const f32x4 ac = (rf == 0) ? ac0 : (rf == 1) ? ac1                \
                           : (rf == 2) ? ac2 : ac3;                           \
            _Pragma("unroll")                                                 \
            for (int r = 0; r < 4; ++r) {                                     \
                float e = __builtin_amdgcn_exp2f(fmaf(ac[r], Kc, -Kc));       \
                if (dg_ && (rb_ + quad * 4 + r == C)) e = 0.f; /* j == i */   \
                lsum[rf][r] += e;                                             \
                cs[(CS0) + g] += e;                                           \
            }                                                                 \
        }                                                                     \
    }                                                                         \
} while (0)

    asm volatile("s_waitcnt vmcnt(0)" ::: "memory");
    __builtin_amdgcn_s_barrier();
    COMPUTE(0, 0);                   // chunk 0
    __builtin_amdgcn_s_barrier();    // all waves done reading buf
    STAGE(CT);                       // chunk 1
    asm volatile("s_waitcnt vmcnt(0)" ::: "memory");
    __builtin_amdgcn_s_barrier();
    COMPUTE(CT, 4);                  // chunk 1

    // ---- row sums -> partial[b][rows of a] -------------------------------
    #pragma unroll
    for (int rf = 0; rf < 4; ++rf)
        #pragma unroll
        for (int r = 0; r < 4; ++r) {
            float v = lsum[rf][r];
            v += __shfl_xor(v, 1);
            v += __shfl_xor(v, 2);
            v += __shfl_xor(v, 4);
            v += __shfl_xor(v, 8);
            lsum[rf][r] = v;
        }
    if (l15 == 0) {
        #pragma unroll
        for (int rf = 0; rf < 4; ++rf)
            #pragma unroll
            for (int r = 0; r < 4; ++r) {
                int row = rw + rf * 16 + quad * 4 + r;
                partial[b * N_ROWS + row] = lsum[rf][r];
            }
    }

    // ---- col sums -> partial[a][rows of b] (skip on diagonal) ------------
    #pragma unroll
    for (int g = 0; g < 8; ++g) {
        float v = cs[g];
        v += __shfl_xor(v, 16);      // sum across quads (rows, same col)
        v += __shfl_xor(v, 32);
        if (lane < 16) colred[wave][g * 16 + l15] = v;
    }
    __syncthreads();
    if (!isdiag) {
        float s = colred[0][t] + colred[1][t];
        partial[a * N_ROWS + b * RB + t] = s;
    }
}

// ---- Kernel 3: per-row loss. 128 blocks x 256 thr; wave w sums slots
// w*16..w*16+15 for 64 rows (coalesced 256B loads), combine via LDS.
__global__ void kreduce(const float* __restrict__ partial,
                        const float* __restrict__ pos,
                        float* __restrict__ bsum) {
    __shared__ float red[4][64];
    int wave = threadIdx.x >> 6;
    int lane = threadIdx.x & 63;
    int row0 = blockIdx.x * 64;
    float L = 0.f;
    #pragma unroll
    for (int p = 0; p < 16; ++p)
        L += partial[(size_t)(wave * 16 + p) * N_ROWS + row0 + lane];
    red[wave][lane] = L;
    __syncthreads();
    if (wave == 0) {
        float Lt = red[0][lane] + red[1][lane] + red[2][lane] + red[3][lane];
        int row = row0 + lane;
        const float invT = 14.285714285714286f;
        // loss_i = (1 - pos_i)/T + ln2 * log2(L)   (v_log_f32 is log2)
        float loss = invT * (1.0f - pos[row])
                   + 0.6931471805599453f * __builtin_amdgcn_logf(Lt);
        #pragma unroll
        for (int off = 1; off < 64; off <<= 1) loss += __shfl_xor(loss, off);
        if (lane == 0) bsum[blockIdx.x] = loss;
    }
}

// ---- Kernel 4: final 128 -> 1 --------------------------------------------
__global__ void kfinal(const float* __restrict__ bsum, float* __restrict__ out) {
    int lane = threadIdx.x;
    float v = bsum[lane] + bsum[lane + 64];
    #pragma unroll
    for (int off = 1; off < 64; off <<= 1) v += __shfl_xor(v, off);
    if (lane == 0) out[0] = v * (1.0f / 8192.0f);
}

extern "C" void kernel_launch(void* const* d_in, const int* in_sizes, int n_in,
                              void* d_out, int out_size, void* d_ws, size_t ws_size,
                              hipStream_t stream) {
    const float* feat = (const float*)d_in[0];
    float* out = (float*)d_out;
    char* ws = (char*)d_ws;
    unsigned short* fb      = (unsigned short*)ws;                    // 4 MB bf16 (swizzled rows)
    float*          partial = (float*)(ws + (4u << 20));              // 2 MB (64 slots x 8192)
    float*          pos     = (float*)(ws + (6u << 20));              // 32 KB
    float*          bsum    = (float*)(ws + (6u << 20) + (1u << 15)); // 512 B

    knorm<<<N_ROWS / 4, 256, 0, stream>>>(feat, fb, pos);
    kmain<<<NPAIR, 128, 0, stream>>>(fb, partial);
    kreduce<<<N_ROWS / 64, 256, 0, stream>>>(partial, pos, bsum);
    kfinal<<<1, 64, 0, stream>>>(bsum, out);
}

// Round 12
// 99.034 us; speedup vs baseline: 1.1241x; 1.0476x over previous
//
#include <hip/hip_runtime.h>
#include <stdint.h>

#define N_ROWS 8192
#define FEAT   256
#define RB     128                    // rows per unit block
#define NB     (N_ROWS / RB)          // 64 row-blocks
#define NPAIR  (NB * (NB + 1) / 2)    // 2080 (a<=b) pairs
#define NSLOT  NB                     // 64 partial slots per row (perfectly packed)
#define CT     64                     // cols staged per chunk (32 KB)

typedef __bf16 bf16x8 __attribute__((ext_vector_type(8)));
typedef float  f32x4  __attribute__((ext_vector_type(4)));

__device__ __forceinline__ unsigned short f2bf(float x) {
    union { float f; uint32_t u; } v; v.f = x;
    uint32_t u = v.u;
    return (unsigned short)((u + 0x7FFFu + ((u >> 16) & 1u)) >> 16);
}

__device__ __forceinline__ void gld16(const unsigned short* g, unsigned short* l) {
    // direct global->LDS, 16 B per lane; LDS dest wave-linear (it is)
    __builtin_amdgcn_global_load_lds((__attribute__((address_space(1))) void*)g,
                                     (__attribute__((address_space(3))) void*)l,
                                     16, 0, 0);
}

// ---- Kernel 1: normalize rows -> bf16 copy (16B-chunk XOR-swizzled rows);
//      fused positive-pair dot. 4 waves/block = 4 consecutive rows.
__global__ void knorm(const float* __restrict__ feat,
                      unsigned short* __restrict__ fb,
                      float* __restrict__ pos) {
    __shared__ float ex[4][FEAT];
    int wave = threadIdx.x >> 6;
    int lane = threadIdx.x & 63;
    int row  = blockIdx.x * 4 + wave;
    float4 v = ((const float4*)(feat + row * FEAT))[lane];
    float ss = v.x*v.x + v.y*v.y + v.z*v.z + v.w*v.w;
    #pragma unroll
    for (int off = 1; off < 64; off <<= 1) ss += __shfl_xor(ss, off);
    float inv = 1.0f / fmaxf(sqrtf(ss), 1e-12f);
    float4 o; o.x = v.x*inv; o.y = v.y*inv; o.z = v.z*inv; o.w = v.w*inv;
    ushort4 b;
    b.x = f2bf(o.x); b.y = f2bf(o.y); b.z = f2bf(o.z); b.w = f2bf(o.w);
    int sidx = (((lane >> 1) ^ (row & 7)) << 1) | (lane & 1);
    ((ushort4*)(fb + row * FEAT))[sidx] = b;
    ((float4*)ex[wave])[lane] = o;
    __syncthreads();
    float4 p = ((float4*)ex[wave ^ 1])[lane];
    float d = o.x*p.x + o.y*p.y + o.z*p.z + o.w*p.w;
    #pragma unroll
    for (int off = 1; off < 64; off <<= 1) d += __shfl_xor(d, off);
    if (lane == 0) pos[row] = d;
}

// ---- Kernel 2: SYMMETRIC LDS-staged f@f^T exp-sum, 4-blocks/CU -----------
// Unit (a<=b): 128 A-rows x 128 B-cols, computed once; exp credited to both
// row sums (rows of a, slot b) and col sums (rows of b, slot a). Perfectly
// packed: every row-block gets all 64 slots written exactly once (diag unit
// writes row-side only). Sized for residency (the R3/R8/R11 lesson): 4
// waves x 32 rows (af[2][8]=64 regs, total ~116 <= 128 -> 4 waves/SIMD) +
// single 32KB staging buffer + 2KB colred -> min(LDS,VGPR) = 4 blocks/CU.
// Intra-block barrier stalls are covered by the other independent-phase
// blocks on the CU (m114 mechanism); LDS staging keeps the per-CU VMEM
// instruction count at ~1/4 of L2-direct. R11 (64-row waves, half DS) was
// tested clean and lost: 2 waves/SIMD latency exposure > DS savings.
// This config is the measured optimum of the family (R9: total 99.76 us).
__global__ __launch_bounds__(256, 4)
void kmain(const unsigned short* __restrict__ fb, float* __restrict__ partial) {
    __shared__ unsigned short buf[CT * FEAT];    // 32 KB (single buffer)
    __shared__ float colred[4][RB];              //  2 KB
    const int t    = threadIdx.x;
    const int lane = t & 63;
    const int wave = t >> 6;          // 0..3
    const int quad = lane >> 4;       // 0..3
    const int l15  = lane & 15;

    // decode blockIdx.x -> (a, b): pair index row-major over a<=b
    int a = 0, rem = blockIdx.x;
    while (rem >= NB - a) { rem -= NB - a; ++a; }
    const int b = a + rem;
    const bool isdiag = (a == b);

    const int rw    = a * RB + wave * 32;        // this wave's 32 A-rows
    const int cbase = b * RB;                    // this unit's 128 B-cols
    const float Kc = 20.60992915555662f;         // log2(e)/0.07

#define STAGE(CC0) do {                                                       \
    const unsigned short* sp_ = fb + (size_t)(cbase + (CC0)) * FEAT + t * 8;  \
    unsigned short* dp_ = buf + t * 8;                                        \
    _Pragma("unroll")                                                         \
    for (int i_ = 0; i_ < 8; ++i_)                                            \
        gld16(sp_ + i_ * 2048, dp_ + i_ * 2048);                              \
} while (0)

    STAGE(0);          // chunk 0 in flight while we load A fragments

    // A fragments: 32 rows x K=256 resident in registers (64 VGPRs)
    bf16x8 af[2][8];
    #pragma unroll
    for (int rf = 0; rf < 2; ++rf)
        #pragma unroll
        for (int ks = 0; ks < 8; ++ks) {
            int row = rw + rf * 16 + l15;
            int ch  = (ks * 4 + quad) ^ (row & 7);   // undo layout swizzle
            af[rf][ks] = *(const bf16x8*)(fb + row * FEAT + ch * 8);
        }

    float lsum[2][4] = {{0.f,0.f,0.f,0.f},{0.f,0.f,0.f,0.f}};
    float cs[8] = {0.f,0.f,0.f,0.f,0.f,0.f,0.f,0.f};

    // one 64-col chunk from LDS: 4 groups of 16 cols
#define COMPUTE(CC0, CS0) do {                                                \
    _Pragma("unroll")                                                         \
    for (int g = 0; g < 4; ++g) {                                             \
        const int cg = cbase + (CC0) + g * 16;                                \
        const int C  = cg + l15;                                              \
        f32x4 ac0 = {0.f,0.f,0.f,0.f};                                        \
        f32x4 ac1 = {0.f,0.f,0.f,0.f};                                        \
        _Pragma("unroll")                                                     \
        for (int ks = 0; ks < 8; ++ks) {                                      \
            bf16x8 bv = *(const bf16x8*)(buf + (g * 16 + l15) * FEAT          \
                                        + (((ks * 4 + quad) ^ (l15 & 7)) * 8)); \
            ac0 = __builtin_amdgcn_mfma_f32_16x16x32_bf16(af[0][ks], bv, ac0, 0, 0, 0); \
            ac1 = __builtin_amdgcn_mfma_f32_16x16x32_bf16(af[1][ks], bv, ac1, 0, 0, 0); \
        }                                                                     \
        _Pragma("unroll")                                                     \
        for (int rf = 0; rf < 2; ++rf) {                                      \
            const int rb_ = rw + rf * 16;                                     \
            const bool dg_ = (cg == rb_);   /* only on diagonal units */      \
            const f32x4 ac = (rf == 0) ? ac0 : ac1;                           \
            _Pragma("unroll")                                                 \
            for (int r = 0; r < 4; ++r) {                                     \
                float e = __builtin_amdgcn_exp2f(fmaf(ac[r], Kc, -Kc));       \
                if (dg_ && (rb_ + quad * 4 + r == C)) e = 0.f; /* j == i */   \
                lsum[rf][r] += e;                                             \
                cs[(CS0) + g] += e;                                           \
            }                                                                 \
        }                                                                     \
    }                                                                         \
} while (0)

    asm volatile("s_waitcnt vmcnt(0)" ::: "memory");
    __builtin_amdgcn_s_barrier();
    COMPUTE(0, 0);                   // chunk 0
    __builtin_amdgcn_s_barrier();    // all waves done reading buf
    STAGE(CT);                       // chunk 1
    asm volatile("s_waitcnt vmcnt(0)" ::: "memory");
    __builtin_amdgcn_s_barrier();
    COMPUTE(CT, 4);                  // chunk 1

    // ---- row sums -> partial[b][rows of a] -------------------------------
    #pragma unroll
    for (int rf = 0; rf < 2; ++rf)
        #pragma unroll
        for (int r = 0; r < 4; ++r) {
            float v = lsum[rf][r];
            v += __shfl_xor(v, 1);
            v += __shfl_xor(v, 2);
            v += __shfl_xor(v, 4);
            v += __shfl_xor(v, 8);
            lsum[rf][r] = v;
        }
    if (l15 == 0) {
        #pragma unroll
        for (int rf = 0; rf < 2; ++rf)
            #pragma unroll
            for (int r = 0; r < 4; ++r) {
                int row = rw + rf * 16 + quad * 4 + r;
                partial[b * N_ROWS + row] = lsum[rf][r];
            }
    }

    // ---- col sums -> partial[a][rows of b] (skip on diagonal) ------------
    #pragma unroll
    for (int g = 0; g < 8; ++g) {
        float v = cs[g];
        v += __shfl_xor(v, 16);      // sum across quads (rows, same col)
        v += __shfl_xor(v, 32);
        if (lane < 16) colred[wave][g * 16 + l15] = v;
    }
    __syncthreads();
    if (!isdiag && t < RB) {
        float s = colred[0][t] + colred[1][t] + colred[2][t] + colred[3][t];
        partial[a * N_ROWS + b * RB + t] = s;
    }
}

// ---- Kernel 3: per-row loss. 128 blocks x 256 thr; wave w sums slots
// w*16..w*16+15 for 64 rows (coalesced 256B loads), combine via LDS.
__global__ void kreduce(const float* __restrict__ partial,
                        const float* __restrict__ pos,
                        float* __restrict__ bsum) {
    __shared__ float red[4][64];
    int wave = threadIdx.x >> 6;
    int lane = threadIdx.x & 63;
    int row0 = blockIdx.x * 64;
    float L = 0.f;
    #pragma unroll
    for (int p = 0; p < 16; ++p)
        L += partial[(size_t)(wave * 16 + p) * N_ROWS + row0 + lane];
    red[wave][lane] = L;
    __syncthreads();
    if (wave == 0) {
        float Lt = red[0][lane] + red[1][lane] + red[2][lane] + red[3][lane];
        int row = row0 + lane;
        const float invT = 14.285714285714286f;
        // loss_i = (1 - pos_i)/T + ln2 * log2(L)   (v_log_f32 is log2)
        float loss = invT * (1.0f - pos[row])
                   + 0.6931471805599453f * __builtin_amdgcn_logf(Lt);
        #pragma unroll
        for (int off = 1; off < 64; off <<= 1) loss += __shfl_xor(loss, off);
        if (lane == 0) bsum[blockIdx.x] = loss;
    }
}

// ---- Kernel 4: final 128 -> 1 --------------------------------------------
__global__ void kfinal(const float* __restrict__ bsum, float* __restrict__ out) {
    int lane = threadIdx.x;
    float v = bsum[lane] + bsum[lane + 64];
    #pragma unroll
    for (int off = 1; off < 64; off <<= 1) v += __shfl_xor(v, off);
    if (lane == 0) out[0] = v * (1.0f / 8192.0f);
}

extern "C" void kernel_launch(void* const* d_in, const int* in_sizes, int n_in,
                              void* d_out, int out_size, void* d_ws, size_t ws_size,
                              hipStream_t stream) {
    const float* feat = (const float*)d_in[0];
    float* out = (float*)d_out;
    char* ws = (char*)d_ws;
    unsigned short* fb      = (unsigned short*)ws;                    // 4 MB bf16 (swizzled rows)
    float*          partial = (float*)(ws + (4u << 20));              // 2 MB (64 slots x 8192)
    float*          pos     = (float*)(ws + (6u << 20));              // 32 KB
    float*          bsum    = (float*)(ws + (6u << 20) + (1u << 15)); // 512 B

    knorm<<<N_ROWS / 4, 256, 0, stream>>>(feat, fb, pos);
    kmain<<<NPAIR, 256, 0, stream>>>(fb, partial);
    kreduce<<<N_ROWS / 64, 256, 0, stream>>>(partial, pos, bsum);
    kfinal<<<1, 64, 0, stream>>>(bsum, out);
}

// Round 13
// 97.907 us; speedup vs baseline: 1.1370x; 1.0115x over previous
//
#include <hip/hip_runtime.h>
#include <stdint.h>

#define N_ROWS 8192
#define FEAT   256
#define RB     128                    // rows per unit block
#define NB     (N_ROWS / RB)          // 64 row-blocks
#define NPAIR  (NB * (NB + 1) / 2)    // 2080 (a<=b) pairs
#define NSLOT  NB                     // 64 partial slots per row (perfectly packed)
#define CT     64                     // cols staged per chunk (32 KB)

typedef __bf16 bf16x8 __attribute__((ext_vector_type(8)));
typedef float  f32x4  __attribute__((ext_vector_type(4)));

__device__ __forceinline__ unsigned short f2bf(float x) {
    union { float f; uint32_t u; } v; v.f = x;
    uint32_t u = v.u;
    return (unsigned short)((u + 0x7FFFu + ((u >> 16) & 1u)) >> 16);
}

__device__ __forceinline__ void gld16(const unsigned short* g, unsigned short* l) {
    // direct global->LDS, 16 B per lane; LDS dest wave-linear (it is)
    __builtin_amdgcn_global_load_lds((__attribute__((address_space(1))) void*)g,
                                     (__attribute__((address_space(3))) void*)l,
                                     16, 0, 0);
}

// ---- Kernel 1: normalize rows -> bf16 copy (16B-chunk XOR-swizzled rows);
//      fused positive-pair dot. 4 waves/block = 4 consecutive rows.
__global__ void knorm(const float* __restrict__ feat,
                      unsigned short* __restrict__ fb,
                      float* __restrict__ pos) {
    __shared__ float ex[4][FEAT];
    int wave = threadIdx.x >> 6;
    int lane = threadIdx.x & 63;
    int row  = blockIdx.x * 4 + wave;
    float4 v = ((const float4*)(feat + row * FEAT))[lane];
    float ss = v.x*v.x + v.y*v.y + v.z*v.z + v.w*v.w;
    #pragma unroll
    for (int off = 1; off < 64; off <<= 1) ss += __shfl_xor(ss, off);
    float inv = 1.0f / fmaxf(sqrtf(ss), 1e-12f);
    float4 o; o.x = v.x*inv; o.y = v.y*inv; o.z = v.z*inv; o.w = v.w*inv;
    ushort4 b;
    b.x = f2bf(o.x); b.y = f2bf(o.y); b.z = f2bf(o.z); b.w = f2bf(o.w);
    int sidx = (((lane >> 1) ^ (row & 7)) << 1) | (lane & 1);
    ((ushort4*)(fb + row * FEAT))[sidx] = b;
    ((float4*)ex[wave])[lane] = o;
    __syncthreads();
    float4 p = ((float4*)ex[wave ^ 1])[lane];
    float d = o.x*p.x + o.y*p.y + o.z*p.z + o.w*p.w;
    #pragma unroll
    for (int off = 1; off < 64; off <<= 1) d += __shfl_xor(d, off);
    if (lane == 0) pos[row] = d;
}

// ---- Kernel 2: SYMMETRIC LDS-staged f@f^T exp-sum, 4-blocks/CU -----------
// R9/R12 structure, byte-identical except launch_bounds. Allocator finding
// (R1/R10/R12): with min-waves >= 2 on an MFMA kernel the unified budget
// (512/min_waves) is split EVENLY arch/acc -- (256,4) gave budget 128 ->
// arch cap 64, and af[2][8]=64 consumed it, spilling lsum/cs/addressing
// (37 MB scratch traffic, VGPR_Count=64, WRITE_SIZE 39.5 MB). (256,2) ->
// budget 256 -> arch cap 128 >= the ~114 actually needed -> no spill; the
// real unified footprint (~120) still lets the HW run 4 waves/SIMD (pool
// 512/SIMD; min-waves is an allocation floor, not an occupancy cap), and
// LDS 34.8 KB still admits 4 blocks/CU.
__global__ __launch_bounds__(256, 2)
void kmain(const unsigned short* __restrict__ fb, float* __restrict__ partial) {
    __shared__ unsigned short buf[CT * FEAT];    // 32 KB (single buffer)
    __shared__ float colred[4][RB];              //  2 KB
    const int t    = threadIdx.x;
    const int lane = t & 63;
    const int wave = t >> 6;          // 0..3
    const int quad = lane >> 4;       // 0..3
    const int l15  = lane & 15;

    // decode blockIdx.x -> (a, b): pair index row-major over a<=b
    int a = 0, rem = blockIdx.x;
    while (rem >= NB - a) { rem -= NB - a; ++a; }
    const int b = a + rem;
    const bool isdiag = (a == b);

    const int rw    = a * RB + wave * 32;        // this wave's 32 A-rows
    const int cbase = b * RB;                    // this unit's 128 B-cols
    const float Kc = 20.60992915555662f;         // log2(e)/0.07

#define STAGE(CC0) do {                                                       \
    const unsigned short* sp_ = fb + (size_t)(cbase + (CC0)) * FEAT + t * 8;  \
    unsigned short* dp_ = buf + t * 8;                                        \
    _Pragma("unroll")                                                         \
    for (int i_ = 0; i_ < 8; ++i_)                                            \
        gld16(sp_ + i_ * 2048, dp_ + i_ * 2048);                              \
} while (0)

    STAGE(0);          // chunk 0 in flight while we load A fragments

    // A fragments: 32 rows x K=256 resident in registers (64 VGPRs)
    bf16x8 af[2][8];
    #pragma unroll
    for (int rf = 0; rf < 2; ++rf)
        #pragma unroll
        for (int ks = 0; ks < 8; ++ks) {
            int row = rw + rf * 16 + l15;
            int ch  = (ks * 4 + quad) ^ (row & 7);   // undo layout swizzle
            af[rf][ks] = *(const bf16x8*)(fb + row * FEAT + ch * 8);
        }

    float lsum[2][4] = {{0.f,0.f,0.f,0.f},{0.f,0.f,0.f,0.f}};
    float cs[8] = {0.f,0.f,0.f,0.f,0.f,0.f,0.f,0.f};

    // one 64-col chunk from LDS: 4 groups of 16 cols
#define COMPUTE(CC0, CS0) do {                                                \
    _Pragma("unroll")                                                         \
    for (int g = 0; g < 4; ++g) {                                             \
        const int cg = cbase + (CC0) + g * 16;                                \
        const int C  = cg + l15;                                              \
        f32x4 ac0 = {0.f,0.f,0.f,0.f};                                        \
        f32x4 ac1 = {0.f,0.f,0.f,0.f};                                        \
        _Pragma("unroll")                                                     \
        for (int ks = 0; ks < 8; ++ks) {                                      \
            bf16x8 bv = *(const bf16x8*)(buf + (g * 16 + l15) * FEAT          \
                                        + (((ks * 4 + quad) ^ (l15 & 7)) * 8)); \
            ac0 = __builtin_amdgcn_mfma_f32_16x16x32_bf16(af[0][ks], bv, ac0, 0, 0, 0); \
            ac1 = __builtin_amdgcn_mfma_f32_16x16x32_bf16(af[1][ks], bv, ac1, 0, 0, 0); \
        }                                                                     \
        _Pragma("unroll")                                                     \
        for (int rf = 0; rf < 2; ++rf) {                                      \
            const int rb_ = rw + rf * 16;                                     \
            const bool dg_ = (cg == rb_);   /* only on diagonal units */      \
            const f32x4 ac = (rf == 0) ? ac0 : ac1;                           \
            _Pragma("unroll")                                                 \
            for (int r = 0; r < 4; ++r) {                                     \
                float e = __builtin_amdgcn_exp2f(fmaf(ac[r], Kc, -Kc));       \
                if (dg_ && (rb_ + quad * 4 + r == C)) e = 0.f; /* j == i */   \
                lsum[rf][r] += e;                                             \
                cs[(CS0) + g] += e;                                           \
            }                                                                 \
        }                                                                     \
    }                                                                         \
} while (0)

    asm volatile("s_waitcnt vmcnt(0)" ::: "memory");
    __builtin_amdgcn_s_barrier();
    COMPUTE(0, 0);                   // chunk 0
    __builtin_amdgcn_s_barrier();    // all waves done reading buf
    STAGE(CT);                       // chunk 1
    asm volatile("s_waitcnt vmcnt(0)" ::: "memory");
    __builtin_amdgcn_s_barrier();
    COMPUTE(CT, 4);                  // chunk 1

    // ---- row sums -> partial[b][rows of a] -------------------------------
    #pragma unroll
    for (int rf = 0; rf < 2; ++rf)
        #pragma unroll
        for (int r = 0; r < 4; ++r) {
            float v = lsum[rf][r];
            v += __shfl_xor(v, 1);
            v += __shfl_xor(v, 2);
            v += __shfl_xor(v, 4);
            v += __shfl_xor(v, 8);
            lsum[rf][r] = v;
        }
    if (l15 == 0) {
        #pragma unroll
        for (int rf = 0; rf < 2; ++rf)
            #pragma unroll
            for (int r = 0; r < 4; ++r) {
                int row = rw + rf * 16 + quad * 4 + r;
                partial[b * N_ROWS + row] = lsum[rf][r];
            }
    }

    // ---- col sums -> partial[a][rows of b] (skip on diagonal) ------------
    #pragma unroll
    for (int g = 0; g < 8; ++g) {
        float v = cs[g];
        v += __shfl_xor(v, 16);      // sum across quads (rows, same col)
        v += __shfl_xor(v, 32);
        if (lane < 16) colred[wave][g * 16 + l15] = v;
    }
    __syncthreads();
    if (!isdiag && t < RB) {
        float s = colred[0][t] + colred[1][t] + colred[2][t] + colred[3][t];
        partial[a * N_ROWS + b * RB + t] = s;
    }
}

// ---- Kernel 3: per-row loss. 128 blocks x 256 thr; wave w sums slots
// w*16..w*16+15 for 64 rows (coalesced 256B loads), combine via LDS.
__global__ void kreduce(const float* __restrict__ partial,
                        const float* __restrict__ pos,
                        float* __restrict__ bsum) {
    __shared__ float red[4][64];
    int wave = threadIdx.x >> 6;
    int lane = threadIdx.x & 63;
    int row0 = blockIdx.x * 64;
    float L = 0.f;
    #pragma unroll
    for (int p = 0; p < 16; ++p)
        L += partial[(size_t)(wave * 16 + p) * N_ROWS + row0 + lane];
    red[wave][lane] = L;
    __syncthreads();
    if (wave == 0) {
        float Lt = red[0][lane] + red[1][lane] + red[2][lane] + red[3][lane];
        int row = row0 + lane;
        const float invT = 14.285714285714286f;
        // loss_i = (1 - pos_i)/T + ln2 * log2(L)   (v_log_f32 is log2)
        float loss = invT * (1.0f - pos[row])
                   + 0.6931471805599453f * __builtin_amdgcn_logf(Lt);
        #pragma unroll
        for (int off = 1; off < 64; off <<= 1) loss += __shfl_xor(loss, off);
        if (lane == 0) bsum[blockIdx.x] = loss;
    }
}

// ---- Kernel 4: final 128 -> 1 --------------------------------------------
__global__ void kfinal(const float* __restrict__ bsum, float* __restrict__ out) {
    int lane = threadIdx.x;
    float v = bsum[lane] + bsum[lane + 64];
    #pragma unroll
    for (int off = 1; off < 64; off <<= 1) v += __shfl_xor(v, off);
    if (lane == 0) out[0] = v * (1.0f / 8192.0f);
}

extern "C" void kernel_launch(void* const* d_in, const int* in_sizes, int n_in,
                              void* d_out, int out_size, void* d_ws, size_t ws_size,
                              hipStream_t stream) {
    const float* feat = (const float*)d_in[0];
    float* out = (float*)d_out;
    char* ws = (char*)d_ws;
    unsigned short* fb      = (unsigned short*)ws;                    // 4 MB bf16 (swizzled rows)
    float*          partial = (float*)(ws + (4u << 20));              // 2 MB (64 slots x 8192)
    float*          pos     = (float*)(ws + (6u << 20));              // 32 KB
    float*          bsum    = (float*)(ws + (6u << 20) + (1u << 15)); // 512 B

    knorm<<<N_ROWS / 4, 256, 0, stream>>>(feat, fb, pos);
    kmain<<<NPAIR, 256, 0, stream>>>(fb, partial);
    kreduce<<<N_ROWS / 64, 256, 0, stream>>>(partial, pos, bsum);
    kfinal<<<1, 64, 0, stream>>>(bsum, out);
}